// Round 4
// baseline (243.330 us; speedup 1.0000x reference)
//
#include <hip/hip_runtime.h>

#define EPSF 1e-8f

// Dimensions (compile-time constants)
#define B_  32
#define C_  16
#define L_  128
#define D_  768
#define D4_ 192   // D/4
#define P_  196
#define OM_ 10
#define OE_ 10
#define R_  36

// ---------- small helpers ----------
__device__ __forceinline__ float4 f4add(float4 a, float4 b){
  return make_float4(a.x+b.x, a.y+b.y, a.z+b.z, a.w+b.w);
}
__device__ __forceinline__ float4 f4scale(float4 a, float s){
  return make_float4(a.x*s, a.y*s, a.z*s, a.w*s);
}
__device__ __forceinline__ float f4dot(float4 a, float4 b){
  return a.x*b.x + a.y*b.y + a.z*b.z + a.w*b.w;
}
__device__ __forceinline__ float wave_sum(float v){
  #pragma unroll
  for (int off = 32; off > 0; off >>= 1) v += __shfl_down(v, off);
  return v;  // valid on lane 0
}

// ================= MEGA: ALL input streaming in one dispatch =================
// Block table (192 threads each):
//   [0,5120)       eof reduce: block per g=(bc,j), 36 rows -> E_BAR[g]
//   [5120,8704)    eif partials: N=512, CH=7, RPC=28
//   [8704,10752)   etf partials: N=512, CH=4, RPC=32, mask=etm, msum+128
//   [10752,11392)  mof partials: N=320, CH=2, RPC=18
//   [11392,11616)  mif partials: N=32,  CH=7, RPC=28
//   [11616,11744)  mtf partials: N=32,  CH=4, RPC=32, mask=mtm, msum+0
__global__ __launch_bounds__(192)
void mega_k(const float* __restrict__ eofp, const float* __restrict__ eif,
            const float* __restrict__ etf, const float* __restrict__ mof,
            const float* __restrict__ mif, const float* __restrict__ mtf,
            const float* __restrict__ etm, const float* __restrict__ mtm,
            float* __restrict__ e_bar,
            float* __restrict__ part_eif, float* __restrict__ part_etf,
            float* __restrict__ part_mof, float* __restrict__ part_mif,
            float* __restrict__ part_mtf, float* __restrict__ msum)
{
  int blk = blockIdx.x;
  int t = threadIdx.x;

  if (blk < 5120) {
    // ---- eof reduce to e_bar ----
    const float4* ep = (const float4*)eofp + (size_t)blk * R_ * D4_;
    float4 acc = make_float4(0.f, 0.f, 0.f, 0.f);
    #pragma unroll 6
    for (int r = 0; r < R_; ++r)
      acc = f4add(acc, ep[(size_t)r * D4_ + t]);
    ((float4*)e_bar)[(size_t)blk * D4_ + t] = f4scale(acc, 1.f / 36.f);
    return;
  }

  const float* in; const float* mask = nullptr;
  float* part; float* ms = nullptr;
  int ROWS, CH, RPC;
  if (blk < 8704)       { blk -= 5120; in = eif; part = part_eif; ROWS = 196; CH = 7; RPC = 28; }
  else if (blk < 10752) { blk -= 8704; in = etf; mask = etm; ms = msum + 128;
                          part = part_etf; ROWS = 128; CH = 4; RPC = 32; }
  else if (blk < 11392) { blk -= 10752; in = mof; part = part_mof; ROWS = 36; CH = 2; RPC = 18; }
  else if (blk < 11616) { blk -= 11392; in = mif; part = part_mif; ROWS = 196; CH = 7; RPC = 28; }
  else                  { blk -= 11616; in = mtf; mask = mtm; ms = msum;
                          part = part_mtf; ROWS = 128; CH = 4; RPC = 32; }

  int g = blk / CH, ch = blk - g * CH;
  int r0 = ch * RPC;
  int r1 = r0 + RPC; if (r1 > ROWS) r1 = ROWS;
  const float4* inp = (const float4*)in + (size_t)g * ROWS * D4_;
  float4 acc = make_float4(0.f, 0.f, 0.f, 0.f);
  if (mask) {
    const float* mrow = mask + (size_t)g * ROWS;
    float msacc = 0.f;
    #pragma unroll 4
    for (int r = r0; r < r1; ++r) {
      float w = mrow[r];
      float4 v = inp[(size_t)r * D4_ + t];
      acc.x += v.x * w; acc.y += v.y * w; acc.z += v.z * w; acc.w += v.w * w;
      msacc += w;
    }
    if (t == 0) ms[blk] = msacc;
  } else {
    #pragma unroll 4
    for (int r = r0; r < r1; ++r)
      acc = f4add(acc, inp[(size_t)r * D4_ + t]);
  }
  ((float4*)part)[(size_t)blk * D4_ + t] = acc;
}

// ================= K_comb: combines + mq + mtet =================
// Block table (256 threads):
//   [0,384)    v_ei combine  (PART_EIF, CH=7, 1/196)
//   [384,768)  v_et combine  (PART_ETF, CH=4, masked, msum+128)
//   [768,792)  v_mi combine  (PART_MIF, CH=7, 1/196)
//   [792,816)  v_mt combine  (PART_MTF, CH=4, masked, msum+0)
//   [816,848)  mq: block per b: mq[b] = sum_i q_i * m_mean[b,i]
//   [848,976)  mtet: 512 waves, span inlined from mtf
__device__ __forceinline__ void combine_body(const float* __restrict__ part,
                                             const float* __restrict__ msum,
                                             float* __restrict__ out,
                                             int secblk, int CH, float invn)
{
  int idx = secblk * 256 + threadIdx.x;      // f4 index into out
  int g = idx / D4_, t = idx - g * D4_;
  const float4* pp = (const float4*)part + (size_t)(g * CH) * D4_ + t;
  float4 acc = make_float4(0.f, 0.f, 0.f, 0.f);
  for (int ch = 0; ch < CH; ++ch) acc = f4add(acc, pp[(size_t)ch * D4_]);
  float scale;
  if (msum) {
    float s = 0.f;
    for (int ch = 0; ch < CH; ++ch) s += msum[g * CH + ch];
    scale = 1.f / fmaxf(s, 1.f);
  } else scale = invn;
  ((float4*)out)[idx] = f4scale(acc, scale);
}

__global__ __launch_bounds__(256)
void comb_k(const float* __restrict__ part_eif, const float* __restrict__ part_etf,
            const float* __restrict__ part_mof, const float* __restrict__ part_mif,
            const float* __restrict__ part_mtf, const float* __restrict__ msum,
            const float* __restrict__ etf, const float* __restrict__ mtf,
            const int* __restrict__ msp, const int* __restrict__ mep,
            const float* __restrict__ mos,
            float* __restrict__ v_ei, float* __restrict__ v_et,
            float* __restrict__ v_mi, float* __restrict__ v_mt,
            float* __restrict__ mq, float* __restrict__ mtet)
{
  int blk = blockIdx.x;
  if (blk < 384)       { combine_body(part_eif, nullptr, v_ei, blk, 7, 1.f/196.f); return; }
  else if (blk < 768)  { combine_body(part_etf, msum + 128, v_et, blk - 384, 4, 0.f); return; }
  else if (blk < 792)  { combine_body(part_mif, nullptr, v_mi, blk - 768, 7, 1.f/196.f); return; }
  else if (blk < 816)  { combine_body(part_mtf, msum, v_mt, blk - 792, 4, 0.f); return; }  // FIXED: msum (was nullptr -> scale 0)
  else if (blk < 848) {
    // ---- mq[b] = sum_i (mos[b,i]/max(|m_i|,eps)) * m_i ----
    __shared__ float sh_n[4][OM_];
    int b = blk - 816;
    int tid = threadIdx.x, wv = tid >> 6, lane = tid & 63;
    int t = tid;                      // f4 col, valid if t < 192
    bool act = (t < D4_);
    float4 m[OM_];
    const float4* pm = (const float4*)part_mof + (size_t)(b * OM_ * 2) * D4_;
    const float inv36 = 1.f / 36.f;
    #pragma unroll
    for (int i = 0; i < OM_; ++i) {
      float4 v = make_float4(0.f, 0.f, 0.f, 0.f);
      if (act) v = f4scale(f4add(pm[(size_t)(2*i) * D4_ + t],
                                 pm[(size_t)(2*i+1) * D4_ + t]), inv36);
      m[i] = v;
      float n = wave_sum(f4dot(v, v));
      if (lane == 0) sh_n[wv][i] = n;
    }
    __syncthreads();
    if (act) {
      float4 acc = make_float4(0.f, 0.f, 0.f, 0.f);
      #pragma unroll
      for (int i = 0; i < OM_; ++i) {
        float nrm = sh_n[0][i] + sh_n[1][i] + sh_n[2][i] + sh_n[3][i];
        float qi = mos[b * OM_ + i] / fmaxf(sqrtf(nrm), EPSF);
        acc = f4add(acc, f4scale(m[i], qi));
      }
      ((float4*)mq)[b * D4_ + t] = acc;
    }
    return;
  } else {
    // ---- mtet: wave per (b,c); span gathered inline ----
    int w = (blk - 848) * 4 + (threadIdx.x >> 6);       // [0,512)
    int lane = threadIdx.x & 63;
    int b = w >> 4;
    const float4* ecls = (const float4*)etf + (size_t)w * L_ * D4_;  // l = 0
    const float4* mb   = (const float4*)mtf + (size_t)b * L_ * D4_;
    int sp = msp[b], ep = mep[b];
    float dt = 0.f, na = 0.f, nb = 0.f;
    #pragma unroll
    for (int k = 0; k < 3; ++k) {
      float4 a = f4scale(f4add(mb[(size_t)sp * D4_ + lane + 64*k],
                               mb[(size_t)ep * D4_ + lane + 64*k]), 0.5f);
      float4 e = ecls[lane + 64*k];
      dt += f4dot(a, e); na += f4dot(a, a); nb += f4dot(e, e);
    }
    dt = wave_sum(dt); na = wave_sum(na); nb = wave_sum(nb);
    if (lane == 0) mtet[w] = dt / fmaxf(sqrtf(na) * sqrtf(nb), EPSF);
  }
}

// ================= K_p: p[g] = eos[g] * (mq[b]·e_bar[g]) / max(|e_bar[g]|,eps) ========
__global__ __launch_bounds__(256)
void p_k(const float* __restrict__ e_bar, const float* __restrict__ mq,
         const float* __restrict__ eos, float* __restrict__ p)
{
  int g = blockIdx.x * 4 + (threadIdx.x >> 6);   // [0,5120) = bc*10+j
  int lane = threadIdx.x & 63;
  int b = g / (C_ * OE_);
  const float4* ep = (const float4*)e_bar + (size_t)g * D4_;
  const float4* mp = (const float4*)mq + (size_t)b * D4_;
  float dt = 0.f, ne = 0.f;
  #pragma unroll
  for (int k = 0; k < 3; ++k) {
    float4 e = ep[lane + 64*k];
    float4 m = mp[lane + 64*k];
    dt += f4dot(m, e); ne += f4dot(e, e);
  }
  dt = wave_sum(dt); ne = wave_sum(ne);
  if (lane == 0) p[g] = eos[g] * dt / fmaxf(sqrtf(ne), EPSF);
}

// ================= K_tail: miei + collapsed GCN + final cosine, block per b =========
__global__ __launch_bounds__(256)
void tail_k(const float* __restrict__ p, const float* __restrict__ mos,
            const float* __restrict__ eos,
            const float* __restrict__ v_mt, const float* __restrict__ v_mi,
            const float* __restrict__ v_et, const float* __restrict__ v_ei,
            const float* __restrict__ mtet, const float* __restrict__ mtei,
            const float* __restrict__ miet,
            float* __restrict__ out)
{
  __shared__ float sh_e0[C_], sh_e1[C_], sh_e2[C_], sh_e3[C_];
  __shared__ float4 sh_m4[D4_], sh_s4[D4_];
  int b = blockIdx.x, tid = threadIdx.x;

  if (tid < C_) {
    int bc = b * C_ + tid;
    float num = 0.f, se = 0.f, sm = 0.f;
    #pragma unroll
    for (int j = 0; j < OE_; ++j) { num += p[bc * OE_ + j]; se += eos[bc * OE_ + j]; }
    #pragma unroll
    for (int i = 0; i < OM_; ++i) sm += mos[b * OM_ + i];
    sh_e3[tid] = num / (sm * se);      // miei
    sh_e0[tid] = mtet[bc];
    sh_e1[tid] = mtei[bc];
    sh_e2[tid] = miet[bc];
  }
  __syncthreads();

  const float invC = 1.f / (float)C_;
  for (int d = tid; d < D_; d += 256) {
    float vmt = v_mt[b * D_ + d], vmi = v_mi[b * D_ + d];
    float nv0 = 0.f, nv1 = 0.f, macc = 0.f;
    #pragma unroll
    for (int c = 0; c < C_; ++c) {
      int bc = b * C_ + c;
      float et = v_et[(size_t)bc * D_ + d];
      float ei = v_ei[(size_t)bc * D_ + d];
      float e0 = sh_e0[c], e1 = sh_e1[c], e2 = sh_e2[c], e3 = sh_e3[c];
      nv0 += e0 * et + e1 * ei;
      nv1 += e2 * et + e3 * ei;
      macc += (vmt * et) * (e0 * vmt + e2 * vmi)
            + (vmt * ei) * (e1 * vmt + e3 * vmi);
    }
    ((float*)sh_m4)[d] = macc * invC;
    ((float*)sh_s4)[d] = vmt * (nv0 * invC) + vmi * (nv1 * invC);
  }
  __syncthreads();

  int wv = tid >> 6, lane = tid & 63;
  for (int c = wv; c < C_; c += 4) {
    const float4* ep = (const float4*)v_et + (size_t)(b * C_ + c) * D4_;
    float dt = 0.f, nm = 0.f, ne = 0.f;
    #pragma unroll
    for (int k = 0; k < 3; ++k) {
      float4 m = sh_m4[lane + 64*k];
      float4 sv = sh_s4[lane + 64*k];
      float4 e = ep[lane + 64*k];
      float4 ent = make_float4(e.x * sv.x, e.y * sv.y, e.z * sv.z, e.w * sv.w);
      dt += f4dot(m, ent); nm += f4dot(m, m); ne += f4dot(ent, ent);
    }
    dt = wave_sum(dt); nm = wave_sum(nm); ne = wave_sum(ne);
    if (lane == 0) out[b * C_ + c] = dt / fmaxf(sqrtf(nm) * sqrtf(ne), EPSF);
  }
}

extern "C" void kernel_launch(void* const* d_in, const int* in_sizes, int n_in,
                              void* d_out, int out_size, void* d_ws, size_t ws_size,
                              hipStream_t stream)
{
  const float* mtf  = (const float*)d_in[0];
  const float* mtm  = (const float*)d_in[1];
  const int*   msp  = (const int*)  d_in[2];
  const int*   mep  = (const int*)  d_in[3];
  const float* mif  = (const float*)d_in[4];
  const float* mof  = (const float*)d_in[5];
  const float* mos  = (const float*)d_in[6];
  const float* etf  = (const float*)d_in[7];
  const float* etm  = (const float*)d_in[8];
  const float* eif  = (const float*)d_in[9];
  const float* eofp = (const float*)d_in[10];
  const float* eos  = (const float*)d_in[11];
  const float* miet = (const float*)d_in[12];
  const float* mtei = (const float*)d_in[13];
  float* out = (float*)d_out;
  float* ws = (float*)d_ws;

  // workspace layout (floats), all regions f4-aligned
  float* E_BAR    = ws;                       // 5120*768 = 3932160
  float* PART_EIF = E_BAR    + 3932160;       // 3584*768 = 2752512
  float* PART_ETF = PART_EIF + 2752512;       // 2048*768 = 1572864
  float* PART_MOF = PART_ETF + 1572864;       //  640*768 =  491520
  float* PART_MIF = PART_MOF + 491520;        //  224*768 =  172032
  float* PART_MTF = PART_MIF + 172032;        //  128*768 =   98304
  float* MSUM     = PART_MTF + 98304;         // 2176 (mtf@[0,128), etf@[128,2176))
  float* V_MT     = MSUM     + 2176;          // 24576
  float* V_MI     = V_MT     + 24576;         // 24576
  float* V_ET     = V_MI     + 24576;         // 393216
  float* V_EI     = V_ET     + 393216;        // 393216
  float* MQ       = V_EI     + 393216;        // 24576
  float* MTET     = MQ       + 24576;         // 512
  float* P_BUF    = MTET     + 512;           // 5120

  // 1) MEGA: all input streaming (eof, eif, etf, mof, mif, mtf)
  mega_k<<<11744, 192, 0, stream>>>(eofp, eif, etf, mof, mif, mtf, etm, mtm,
                                    E_BAR, PART_EIF, PART_ETF, PART_MOF,
                                    PART_MIF, PART_MTF, MSUM);

  // 2) combines + mq + mtet
  comb_k<<<976, 256, 0, stream>>>(PART_EIF, PART_ETF, PART_MOF, PART_MIF,
                                  PART_MTF, MSUM, etf, mtf, msp, mep, mos,
                                  V_EI, V_ET, V_MI, V_MT, MQ, MTET);

  // 3) p from e_bar (L3-resident) and mq
  p_k<<<1280, 256, 0, stream>>>(E_BAR, MQ, eos, P_BUF);

  // 4) miei + GCN + final cosine
  tail_k<<<B_, 256, 0, stream>>>(P_BUF, mos, eos, V_MT, V_MI, V_ET, V_EI,
                                 MTET, mtei, miet, out);
}

// Round 5
// 226.018 us; speedup vs baseline: 1.0766x; 1.0766x over previous
//
#include <hip/hip_runtime.h>

#define EPSF 1e-8f

// Dimensions (compile-time constants)
#define B_  32
#define C_  16
#define L_  128
#define D_  768
#define D4_ 192   // D/4
#define P_  196
#define OM_ 10
#define OE_ 10
#define R_  36

// ---------- small helpers ----------
__device__ __forceinline__ float4 f4add(float4 a, float4 b){
  return make_float4(a.x+b.x, a.y+b.y, a.z+b.z, a.w+b.w);
}
__device__ __forceinline__ float4 f4scale(float4 a, float s){
  return make_float4(a.x*s, a.y*s, a.z*s, a.w*s);
}
__device__ __forceinline__ float f4dot(float4 a, float4 b){
  return a.x*b.x + a.y*b.y + a.z*b.z + a.w*b.w;
}
__device__ __forceinline__ float wave_sum(float v){
  #pragma unroll
  for (int off = 32; off > 0; off >>= 1) v += __shfl_down(v, off);
  return v;  // valid on lane 0
}

// ================= D1: mof -> m_mean[b,i], q[b,i]; one block per (b,i) =================
__global__ __launch_bounds__(192)
void mof_k(const float* __restrict__ mof, const float* __restrict__ mos,
           float* __restrict__ m_mean, float* __restrict__ q)
{
  int blk = blockIdx.x;                  // (b*OM + i)
  int t = threadIdx.x, wv = t >> 6, lane = t & 63;
  const float4* inp = (const float4*)mof + (size_t)blk * R_ * D4_;
  float4 acc = make_float4(0.f, 0.f, 0.f, 0.f);
  #pragma unroll 6
  for (int r = 0; r < R_; ++r)
    acc = f4add(acc, inp[(size_t)r * D4_ + t]);
  acc = f4scale(acc, 1.f / 36.f);
  ((float4*)m_mean)[(size_t)blk * D4_ + t] = acc;
  __shared__ float sh[3];
  float n = wave_sum(f4dot(acc, acc));
  if (lane == 0) sh[wv] = n;
  __syncthreads();
  if (t == 0) q[blk] = mos[blk] / fmaxf(sqrtf(sh[0] + sh[1] + sh[2]), EPSF);
}

// ================= D2: eof-dot + all remaining partials, one dispatch =================
// Block table (192 threads each):
//   [0,1707)      eof-dot: 3 waves/block, wave -> g = blk*3+wave (g<5120), writes p[g]
//   [1707,5291)   eif partials: N=512, CH=7, RPC=28
//   [5291,7339)   etf partials: N=512, CH=4, RPC=32, mask=etm, msum+128
//   [7339,7563)   mif partials: N=32,  CH=7, RPC=28
//   [7563,7691)   mtf partials: N=32,  CH=4, RPC=32, mask=mtm, msum+0
__global__ __launch_bounds__(192)
void mega2_k(const float* __restrict__ eofp, const float* __restrict__ eif,
             const float* __restrict__ etf, const float* __restrict__ mif,
             const float* __restrict__ mtf,
             const float* __restrict__ etm, const float* __restrict__ mtm,
             const float* __restrict__ m_mean, const float* __restrict__ q,
             const float* __restrict__ eos,
             float* __restrict__ part_eif, float* __restrict__ part_etf,
             float* __restrict__ part_mif, float* __restrict__ part_mtf,
             float* __restrict__ msum, float* __restrict__ p)
{
  int blk = blockIdx.x;
  int t = threadIdx.x;

  if (blk < 1707) {
    // ---- eof fused mean+norm+dot (write-free except p) ----
    int wave = t >> 6, lane = t & 63;
    int g = blk * 3 + wave;              // g = bc*10 + j
    if (g >= 5120) return;
    int b = g / (C_ * OE_);
    const float4* ep = (const float4*)eofp + (size_t)g * R_ * D4_;
    float4 a0 = make_float4(0,0,0,0), a1 = a0, a2 = a0;
    #pragma unroll 4
    for (int r = 0; r < R_; ++r) {
      const float4* row = ep + (size_t)r * D4_;
      a0 = f4add(a0, row[lane]);
      a1 = f4add(a1, row[lane + 64]);
      a2 = f4add(a2, row[lane + 128]);
    }
    const float inv36 = 1.f / 36.f;
    a0 = f4scale(a0, inv36); a1 = f4scale(a1, inv36); a2 = f4scale(a2, inv36);
    float nrm = f4dot(a0, a0) + f4dot(a1, a1) + f4dot(a2, a2);
    float s = 0.f;
    const float4* mp = (const float4*)m_mean + (size_t)b * OM_ * D4_;
    #pragma unroll
    for (int i = 0; i < OM_; ++i) {
      const float4* mr = mp + (size_t)i * D4_;
      float di = f4dot(a0, mr[lane]) + f4dot(a1, mr[lane + 64]) + f4dot(a2, mr[lane + 128]);
      s += q[b * OM_ + i] * di;
    }
    s = wave_sum(s); nrm = wave_sum(nrm);
    if (lane == 0) p[g] = eos[g] * s / fmaxf(sqrtf(nrm), EPSF);
    return;
  }

  blk -= 1707;
  const float* in; const float* mask = nullptr;
  float* part; float* ms = nullptr;
  int ROWS, CH, RPC;
  if (blk < 3584)      { in = eif; part = part_eif; ROWS = 196; CH = 7; RPC = 28; }
  else if (blk < 5632) { blk -= 3584; in = etf; mask = etm; ms = msum + 128;
                         part = part_etf; ROWS = 128; CH = 4; RPC = 32; }
  else if (blk < 5856) { blk -= 5632; in = mif; part = part_mif; ROWS = 196; CH = 7; RPC = 28; }
  else                 { blk -= 5856; in = mtf; mask = mtm; ms = msum;
                         part = part_mtf; ROWS = 128; CH = 4; RPC = 32; }

  int g = blk / CH, ch = blk - g * CH;
  int r0 = ch * RPC;
  int r1 = r0 + RPC; if (r1 > ROWS) r1 = ROWS;
  const float4* inp = (const float4*)in + (size_t)g * ROWS * D4_;
  float4 acc = make_float4(0.f, 0.f, 0.f, 0.f);
  if (mask) {
    const float* mrow = mask + (size_t)g * ROWS;
    float msacc = 0.f;
    #pragma unroll 4
    for (int r = r0; r < r1; ++r) {
      float w = mrow[r];
      float4 v = inp[(size_t)r * D4_ + t];
      acc.x += v.x * w; acc.y += v.y * w; acc.z += v.z * w; acc.w += v.w * w;
      msacc += w;
    }
    if (t == 0) ms[blk] = msacc;
  } else {
    #pragma unroll 4
    for (int r = r0; r < r1; ++r)
      acc = f4add(acc, inp[(size_t)r * D4_ + t]);
  }
  ((float4*)part)[(size_t)blk * D4_ + t] = acc;
}

// ================= D3: combines + mtet =================
// Block table (256 threads):
//   [0,384)    v_ei combine  (PART_EIF, CH=7, 1/196)
//   [384,768)  v_et combine  (PART_ETF, CH=4, masked, msum+128)
//   [768,792)  v_mi combine  (PART_MIF, CH=7, 1/196)
//   [792,816)  v_mt combine  (PART_MTF, CH=4, masked, msum+0)
//   [816,944)  mtet: 512 waves, span inlined from mtf
__device__ __forceinline__ void combine_body(const float* __restrict__ part,
                                             const float* __restrict__ msum,
                                             float* __restrict__ out,
                                             int secblk, int CH, float invn)
{
  int idx = secblk * 256 + threadIdx.x;      // f4 index into out
  int g = idx / D4_, t = idx - g * D4_;
  const float4* pp = (const float4*)part + (size_t)(g * CH) * D4_ + t;
  float4 acc = make_float4(0.f, 0.f, 0.f, 0.f);
  for (int ch = 0; ch < CH; ++ch) acc = f4add(acc, pp[(size_t)ch * D4_]);
  float scale;
  if (msum) {
    float s = 0.f;
    for (int ch = 0; ch < CH; ++ch) s += msum[g * CH + ch];
    scale = 1.f / fmaxf(s, 1.f);
  } else scale = invn;
  ((float4*)out)[idx] = f4scale(acc, scale);
}

__global__ __launch_bounds__(256)
void comb2_k(const float* __restrict__ part_eif, const float* __restrict__ part_etf,
             const float* __restrict__ part_mif, const float* __restrict__ part_mtf,
             const float* __restrict__ msum,
             const float* __restrict__ etf, const float* __restrict__ mtf,
             const int* __restrict__ msp, const int* __restrict__ mep,
             float* __restrict__ v_ei, float* __restrict__ v_et,
             float* __restrict__ v_mi, float* __restrict__ v_mt,
             float* __restrict__ mtet)
{
  int blk = blockIdx.x;
  if (blk < 384)       { combine_body(part_eif, nullptr, v_ei, blk, 7, 1.f/196.f); return; }
  else if (blk < 768)  { combine_body(part_etf, msum + 128, v_et, blk - 384, 4, 0.f); return; }
  else if (blk < 792)  { combine_body(part_mif, nullptr, v_mi, blk - 768, 7, 1.f/196.f); return; }
  else if (blk < 816)  { combine_body(part_mtf, msum, v_mt, blk - 792, 4, 0.f); return; }
  else {
    // ---- mtet: wave per (b,c); span gathered inline ----
    int w = (blk - 816) * 4 + (threadIdx.x >> 6);       // [0,512)
    int lane = threadIdx.x & 63;
    int b = w >> 4;
    const float4* ecls = (const float4*)etf + (size_t)w * L_ * D4_;  // l = 0
    const float4* mb   = (const float4*)mtf + (size_t)b * L_ * D4_;
    int sp = msp[b], ep = mep[b];
    float dt = 0.f, na = 0.f, nb = 0.f;
    #pragma unroll
    for (int k = 0; k < 3; ++k) {
      float4 a = f4scale(f4add(mb[(size_t)sp * D4_ + lane + 64*k],
                               mb[(size_t)ep * D4_ + lane + 64*k]), 0.5f);
      float4 e = ecls[lane + 64*k];
      dt += f4dot(a, e); na += f4dot(a, a); nb += f4dot(e, e);
    }
    dt = wave_sum(dt); na = wave_sum(na); nb = wave_sum(nb);
    if (lane == 0) mtet[w] = dt / fmaxf(sqrtf(na) * sqrtf(nb), EPSF);
  }
}

// ================= D4: miei + collapsed GCN + final cosine, block per b =========
__global__ __launch_bounds__(256)
void tail_k(const float* __restrict__ p, const float* __restrict__ mos,
            const float* __restrict__ eos,
            const float* __restrict__ v_mt, const float* __restrict__ v_mi,
            const float* __restrict__ v_et, const float* __restrict__ v_ei,
            const float* __restrict__ mtet, const float* __restrict__ mtei,
            const float* __restrict__ miet,
            float* __restrict__ out)
{
  __shared__ float sh_e0[C_], sh_e1[C_], sh_e2[C_], sh_e3[C_];
  __shared__ float4 sh_m4[D4_], sh_s4[D4_];
  int b = blockIdx.x, tid = threadIdx.x;

  if (tid < C_) {
    int bc = b * C_ + tid;
    float num = 0.f, se = 0.f, sm = 0.f;
    #pragma unroll
    for (int j = 0; j < OE_; ++j) { num += p[bc * OE_ + j]; se += eos[bc * OE_ + j]; }
    #pragma unroll
    for (int i = 0; i < OM_; ++i) sm += mos[b * OM_ + i];
    sh_e3[tid] = num / (sm * se);      // miei
    sh_e0[tid] = mtet[bc];
    sh_e1[tid] = mtei[bc];
    sh_e2[tid] = miet[bc];
  }
  __syncthreads();

  const float invC = 1.f / (float)C_;
  for (int d = tid; d < D_; d += 256) {
    float vmt = v_mt[b * D_ + d], vmi = v_mi[b * D_ + d];
    float nv0 = 0.f, nv1 = 0.f, macc = 0.f;
    #pragma unroll
    for (int c = 0; c < C_; ++c) {
      int bc = b * C_ + c;
      float et = v_et[(size_t)bc * D_ + d];
      float ei = v_ei[(size_t)bc * D_ + d];
      float e0 = sh_e0[c], e1 = sh_e1[c], e2 = sh_e2[c], e3 = sh_e3[c];
      nv0 += e0 * et + e1 * ei;
      nv1 += e2 * et + e3 * ei;
      macc += (vmt * et) * (e0 * vmt + e2 * vmi)
            + (vmt * ei) * (e1 * vmt + e3 * vmi);
    }
    ((float*)sh_m4)[d] = macc * invC;
    ((float*)sh_s4)[d] = vmt * (nv0 * invC) + vmi * (nv1 * invC);
  }
  __syncthreads();

  int wv = tid >> 6, lane = tid & 63;
  for (int c = wv; c < C_; c += 4) {
    const float4* ep = (const float4*)v_et + (size_t)(b * C_ + c) * D4_;
    float dt = 0.f, nm = 0.f, ne = 0.f;
    #pragma unroll
    for (int k = 0; k < 3; ++k) {
      float4 m = sh_m4[lane + 64*k];
      float4 sv = sh_s4[lane + 64*k];
      float4 e = ep[lane + 64*k];
      float4 ent = make_float4(e.x * sv.x, e.y * sv.y, e.z * sv.z, e.w * sv.w);
      dt += f4dot(m, ent); nm += f4dot(m, m); ne += f4dot(ent, ent);
    }
    dt = wave_sum(dt); nm = wave_sum(nm); ne = wave_sum(ne);
    if (lane == 0) out[b * C_ + c] = dt / fmaxf(sqrtf(nm) * sqrtf(ne), EPSF);
  }
}

extern "C" void kernel_launch(void* const* d_in, const int* in_sizes, int n_in,
                              void* d_out, int out_size, void* d_ws, size_t ws_size,
                              hipStream_t stream)
{
  const float* mtf  = (const float*)d_in[0];
  const float* mtm  = (const float*)d_in[1];
  const int*   msp  = (const int*)  d_in[2];
  const int*   mep  = (const int*)  d_in[3];
  const float* mif  = (const float*)d_in[4];
  const float* mof  = (const float*)d_in[5];
  const float* mos  = (const float*)d_in[6];
  const float* etf  = (const float*)d_in[7];
  const float* etm  = (const float*)d_in[8];
  const float* eif  = (const float*)d_in[9];
  const float* eofp = (const float*)d_in[10];
  const float* eos  = (const float*)d_in[11];
  const float* miet = (const float*)d_in[12];
  const float* mtei = (const float*)d_in[13];
  float* out = (float*)d_out;
  float* ws = (float*)d_ws;

  // workspace layout (floats), all regions f4-aligned
  float* PART_EIF = ws;                       // 3584*768 = 2752512
  float* PART_ETF = PART_EIF + 2752512;       // 2048*768 = 1572864
  float* PART_MIF = PART_ETF + 1572864;       //  224*768 =  172032
  float* PART_MTF = PART_MIF + 172032;        //  128*768 =   98304
  float* MSUM     = PART_MTF + 98304;         // 2176 (mtf@[0,128), etf@[128,2176))
  float* M_MEAN   = MSUM     + 2176;          // 320*768 = 245760
  float* Q        = M_MEAN   + 245760;        // 512 (320 used)
  float* V_MT     = Q        + 512;           // 24576
  float* V_MI     = V_MT     + 24576;         // 24576
  float* V_ET     = V_MI     + 24576;         // 393216
  float* V_EI     = V_ET     + 393216;        // 393216
  float* MTET     = V_EI     + 393216;        // 512
  float* P_BUF    = MTET     + 512;           // 5120

  // D1: mof -> m_mean + q (one block per (b,i), no combine needed)
  mof_k<<<320, 192, 0, stream>>>(mof, mos, M_MEAN, Q);

  // D2: eof-dot (write-free) + eif/etf/mif/mtf partials in ONE dispatch
  mega2_k<<<7691, 192, 0, stream>>>(eofp, eif, etf, mif, mtf, etm, mtm,
                                    M_MEAN, Q, eos,
                                    PART_EIF, PART_ETF, PART_MIF, PART_MTF,
                                    MSUM, P_BUF);

  // D3: combines + mtet
  comb2_k<<<944, 256, 0, stream>>>(PART_EIF, PART_ETF, PART_MIF, PART_MTF,
                                   MSUM, etf, mtf, msp, mep,
                                   V_EI, V_ET, V_MI, V_MT, MTET);

  // D4: miei + GCN + final cosine
  tail_k<<<B_, 256, 0, stream>>>(P_BUF, mos, eos, V_MT, V_MI, V_ET, V_EI,
                                 MTET, mtei, miet, out);
}

// Round 6
// 210.794 us; speedup vs baseline: 1.1543x; 1.0722x over previous
//
#include <hip/hip_runtime.h>

#define EPSF 1e-8f

// Dimensions
#define B_  32
#define C_  16
#define L_  128
#define D_  768
#define D4_ 192   // D/4
#define P_  196
#define OM_ 10
#define OE_ 10
#define R_  36

typedef float f4 __attribute__((ext_vector_type(4)));

__device__ __forceinline__ float f4dot(f4 a, f4 b){ return a.x*b.x + a.y*b.y + a.z*b.z + a.w*b.w; }
__device__ __forceinline__ f4 ldnt(const f4* p){ return __builtin_nontemporal_load(p); }
__device__ __forceinline__ float wave_sum(float v){
  #pragma unroll
  for (int off = 32; off > 0; off >>= 1) v += __shfl_down(v, off);
  return v;  // valid on lane 0
}

// ================= D1: mention-side + mtet =================
// Block table (384 threads = 6 waves):
//   [0,320)    mof: block per (b,i); rows split 18/18 across thread halves -> m_mean, q
//   [320,352)  mif: block per b; rows 98/98 -> v_mi
//   [352,384)  mtf: block per b; rows 64/64, masked -> v_mt
//   [384,470)  mtet: wave per (b,c), 512 waves; span inlined from mtf
__global__ __launch_bounds__(384)
void d1_k(const float* __restrict__ mof, const float* __restrict__ mos,
          const float* __restrict__ mif, const float* __restrict__ mtf,
          const float* __restrict__ mtm, const float* __restrict__ etf,
          const int* __restrict__ msp, const int* __restrict__ mep,
          float* __restrict__ m_mean, float* __restrict__ q,
          float* __restrict__ v_mi, float* __restrict__ v_mt,
          float* __restrict__ mtet)
{
  __shared__ f4 shv[2][D4_];
  __shared__ float shs[4];
  int blk = blockIdx.x, t = threadIdx.x;

  if (blk < 320) {
    // ---- mof -> m_mean[g], q[g]; g = b*10+i ----
    int g = blk;
    int half = t / D4_, col = t - half * D4_;
    const f4* base = (const f4*)mof + (size_t)g * R_ * D4_;
    f4 acc = {0.f, 0.f, 0.f, 0.f};
    int r0 = half * 18;
    #pragma unroll 6
    for (int r = r0; r < r0 + 18; ++r) acc += ldnt(base + (size_t)r * D4_ + col);
    shv[half][col] = acc;
    __syncthreads();
    if (t < D4_) {
      f4 mean = (shv[0][col] + shv[1][col]) * (1.f / 36.f);
      ((f4*)m_mean)[(size_t)g * D4_ + col] = mean;
      float n = wave_sum(f4dot(mean, mean));
      if ((t & 63) == 0) shs[t >> 6] = n;
    }
    __syncthreads();
    if (t == 0) q[g] = mos[g] / fmaxf(sqrtf(shs[0] + shs[1] + shs[2]), EPSF);
    return;
  }
  if (blk < 352) {
    // ---- mif -> v_mi[b] ----
    int b = blk - 320;
    int half = t / D4_, col = t - half * D4_;
    const f4* base = (const f4*)mif + (size_t)b * P_ * D4_;
    f4 acc = {0.f, 0.f, 0.f, 0.f};
    int r0 = half * 98;
    #pragma unroll 4
    for (int r = r0; r < r0 + 98; ++r) acc += ldnt(base + (size_t)r * D4_ + col);
    shv[half][col] = acc;
    __syncthreads();
    if (t < D4_)
      ((f4*)v_mi)[(size_t)b * D4_ + col] = (shv[0][col] + shv[1][col]) * (1.f / 196.f);
    return;
  }
  if (blk < 384) {
    // ---- mtf (masked) -> v_mt[b] ----
    int b = blk - 352;
    int half = t / D4_, col = t - half * D4_;
    const f4* base = (const f4*)mtf + (size_t)b * L_ * D4_;
    const float* mrow = mtm + (size_t)b * L_;
    f4 acc = {0.f, 0.f, 0.f, 0.f};
    float ms = 0.f;
    int r0 = half * 64;
    #pragma unroll 4
    for (int r = r0; r < r0 + 64; ++r) {
      float w = mrow[r];
      acc += ldnt(base + (size_t)r * D4_ + col) * w;
      ms += w;
    }
    shv[half][col] = acc;
    if (t == 0)    shs[0] = ms;
    if (t == D4_)  shs[1] = ms;
    __syncthreads();
    if (t < D4_) {
      float scale = 1.f / fmaxf(shs[0] + shs[1], 1.f);
      ((f4*)v_mt)[(size_t)b * D4_ + col] = (shv[0][col] + shv[1][col]) * scale;
    }
    return;
  }
  {
    // ---- mtet: wave per (b,c) ----
    int w = (blk - 384) * 6 + (t >> 6);
    if (w >= B_ * C_) return;
    int lane = t & 63;
    int b = w >> 4;
    const f4* ecls = (const f4*)etf + (size_t)w * L_ * D4_;  // l = 0
    const f4* mb   = (const f4*)mtf + (size_t)b * L_ * D4_;
    int sp = msp[b], ep = mep[b];
    float dt = 0.f, na = 0.f, nb = 0.f;
    #pragma unroll
    for (int k = 0; k < 3; ++k) {
      f4 a = (mb[(size_t)sp * D4_ + lane + 64*k] + mb[(size_t)ep * D4_ + lane + 64*k]) * 0.5f;
      f4 e = ecls[lane + 64*k];
      dt += f4dot(a, e); na += f4dot(a, a); nb += f4dot(e, e);
    }
    dt = wave_sum(dt); na = wave_sum(na); nb = wave_sum(nb);
    if (lane == 0) mtet[w] = dt / fmaxf(sqrtf(na) * sqrtf(nb), EPSF);
  }
}

// ================= D2: eof-dot + eif/etf partials (all nt streaming) =================
// Block table (192 threads = 3 waves):
//   [0,1707)      eof-dot: wave per g = blk*3+wv (g<5120) -> p[g]
//   [1707,2731)   eif partials: idx=blk-1707, g=idx>>1, ch=idx&1, 98 rows
//   [2731,3755)   etf partials (masked): idx=blk-2731, g=idx>>1, ch=idx&1, 64 rows
__global__ __launch_bounds__(192)
void d2_k(const float* __restrict__ eofp, const float* __restrict__ eif,
          const float* __restrict__ etf, const float* __restrict__ etm,
          const float* __restrict__ m_mean, const float* __restrict__ q,
          const float* __restrict__ eos,
          float* __restrict__ part_eif, float* __restrict__ part_etf,
          float* __restrict__ msum_etf, float* __restrict__ p)
{
  int blk = blockIdx.x, t = threadIdx.x;

  if (blk < 1707) {
    int wave = t >> 6, lane = t & 63;
    int g = blk * 3 + wave;              // g = bc*10 + j
    if (g >= B_ * C_ * OE_) return;
    int b = g / (C_ * OE_);
    const f4* ep = (const f4*)eofp + (size_t)g * R_ * D4_;
    f4 a0 = {0.f,0.f,0.f,0.f}, a1 = a0, a2 = a0;
    #pragma unroll 4
    for (int r = 0; r < R_; ++r) {
      const f4* row = ep + (size_t)r * D4_;
      a0 += ldnt(row + lane);
      a1 += ldnt(row + lane + 64);
      a2 += ldnt(row + lane + 128);
    }
    const float inv36 = 1.f / 36.f;
    a0 *= inv36; a1 *= inv36; a2 *= inv36;
    float nrm = f4dot(a0, a0) + f4dot(a1, a1) + f4dot(a2, a2);
    float s = 0.f;
    const f4* mp = (const f4*)m_mean + (size_t)b * OM_ * D4_;
    #pragma unroll
    for (int i = 0; i < OM_; ++i) {
      const f4* mr = mp + (size_t)i * D4_;
      float di = f4dot(a0, mr[lane]) + f4dot(a1, mr[lane + 64]) + f4dot(a2, mr[lane + 128]);
      s += q[b * OM_ + i] * di;
    }
    s = wave_sum(s); nrm = wave_sum(nrm);
    if (lane == 0) p[g] = eos[g] * s / fmaxf(sqrtf(nrm), EPSF);
    return;
  }
  blk -= 1707;
  if (blk < 1024) {
    // ---- eif partials (CH=2) ----
    int g = blk >> 1, ch = blk & 1;
    const f4* inp = (const f4*)eif + ((size_t)g * P_ + ch * 98) * D4_;
    f4 acc = {0.f,0.f,0.f,0.f};
    #pragma unroll 4
    for (int r = 0; r < 98; ++r) acc += ldnt(inp + (size_t)r * D4_ + t);
    ((f4*)part_eif)[(size_t)blk * D4_ + t] = acc;
    return;
  }
  blk -= 1024;
  {
    // ---- etf partials (CH=2, masked) ----
    int g = blk >> 1, ch = blk & 1;
    const f4* inp = (const f4*)etf + ((size_t)g * L_ + ch * 64) * D4_;
    const float* mrow = etm + (size_t)g * L_ + ch * 64;
    f4 acc = {0.f,0.f,0.f,0.f};
    float ms = 0.f;
    #pragma unroll 4
    for (int r = 0; r < 64; ++r) {
      float w = mrow[r];
      acc += ldnt(inp + (size_t)r * D4_ + t) * w;
      ms += w;
    }
    ((f4*)part_etf)[(size_t)blk * D4_ + t] = acc;
    if (t == 0) msum_etf[blk] = ms;
  }
}

// ================= D3: v_et combine (LDS) + v_ei inline + miei + GCN + final ==========
__global__ __launch_bounds__(384)
void d3_k(const float* __restrict__ part_eif, const float* __restrict__ part_etf,
          const float* __restrict__ msum_etf,
          const float* __restrict__ p, const float* __restrict__ mos,
          const float* __restrict__ eos,
          const float* __restrict__ v_mt, const float* __restrict__ v_mi,
          const float* __restrict__ mtet, const float* __restrict__ mtei,
          const float* __restrict__ miet,
          float* __restrict__ out)
{
  __shared__ float s_vet[C_][D_];                      // 48 KiB
  __shared__ float sh_e0[C_], sh_e1[C_], sh_e2[C_], sh_e3[C_];
  __shared__ float sh_m[D_], sh_s[D_];
  int b = blockIdx.x, t = threadIdx.x;

  // 1) v_et combine into LDS
  for (int it = t; it < C_ * D4_; it += 384) {
    int c = it / D4_, col = it - c * D4_;
    int i2 = (b * C_ + c) * 2;
    f4 a = ((const f4*)part_etf)[(size_t)i2 * D4_ + col]
         + ((const f4*)part_etf)[(size_t)(i2 + 1) * D4_ + col];
    float scale = 1.f / fmaxf(msum_etf[i2] + msum_etf[i2 + 1], 1.f);
    ((f4*)&s_vet[c][0])[col] = a * scale;
  }
  // edges
  if (t < C_) {
    int bc = b * C_ + t;
    float num = 0.f, se = 0.f, sm = 0.f;
    #pragma unroll
    for (int j = 0; j < OE_; ++j) { num += p[bc * OE_ + j]; se += eos[bc * OE_ + j]; }
    #pragma unroll
    for (int i = 0; i < OM_; ++i) sm += mos[b * OM_ + i];
    sh_e3[t] = num / (sm * se);      // miei
    sh_e0[t] = mtet[bc];
    sh_e1[t] = mtei[bc];
    sh_e2[t] = miet[bc];
  }
  __syncthreads();

  // 2) collapsed GCN
  const float invC = 1.f / (float)C_, inv196 = 1.f / 196.f;
  for (int d = t; d < D_; d += 384) {
    float vmt = v_mt[b * D_ + d], vmi = v_mi[b * D_ + d];
    float nv0 = 0.f, nv1 = 0.f, macc = 0.f;
    #pragma unroll
    for (int c = 0; c < C_; ++c) {
      int i2 = (b * C_ + c) * 2;
      float et = s_vet[c][d];
      float ei = (part_eif[(size_t)i2 * D_ + d] + part_eif[(size_t)(i2 + 1) * D_ + d]) * inv196;
      float e0 = sh_e0[c], e1 = sh_e1[c], e2 = sh_e2[c], e3 = sh_e3[c];
      nv0 += e0 * et + e1 * ei;
      nv1 += e2 * et + e3 * ei;
      macc += (vmt * et) * (e0 * vmt + e2 * vmi)
            + (vmt * ei) * (e1 * vmt + e3 * vmi);
    }
    sh_m[d] = macc * invC;
    sh_s[d] = vmt * (nv0 * invC) + vmi * (nv1 * invC);
  }
  __syncthreads();

  // 3) final cosine: wave per c
  int wv = t >> 6, lane = t & 63;
  for (int c = wv; c < C_; c += 6) {
    const f4* ep = (const f4*)&s_vet[c][0];
    const f4* mp = (const f4*)sh_m;
    const f4* sp = (const f4*)sh_s;
    float dt = 0.f, nm = 0.f, ne = 0.f;
    #pragma unroll
    for (int k = 0; k < 3; ++k) {
      f4 m = mp[lane + 64*k];
      f4 sv = sp[lane + 64*k];
      f4 e = ep[lane + 64*k];
      f4 ent = e * sv;
      dt += f4dot(m, ent); nm += f4dot(m, m); ne += f4dot(ent, ent);
    }
    dt = wave_sum(dt); nm = wave_sum(nm); ne = wave_sum(ne);
    if (lane == 0) out[b * C_ + c] = dt / fmaxf(sqrtf(nm) * sqrtf(ne), EPSF);
  }
}

extern "C" void kernel_launch(void* const* d_in, const int* in_sizes, int n_in,
                              void* d_out, int out_size, void* d_ws, size_t ws_size,
                              hipStream_t stream)
{
  const float* mtf  = (const float*)d_in[0];
  const float* mtm  = (const float*)d_in[1];
  const int*   msp  = (const int*)  d_in[2];
  const int*   mep  = (const int*)  d_in[3];
  const float* mif  = (const float*)d_in[4];
  const float* mof  = (const float*)d_in[5];
  const float* mos  = (const float*)d_in[6];
  const float* etf  = (const float*)d_in[7];
  const float* etm  = (const float*)d_in[8];
  const float* eif  = (const float*)d_in[9];
  const float* eofp = (const float*)d_in[10];
  const float* eos  = (const float*)d_in[11];
  const float* miet = (const float*)d_in[12];
  const float* mtei = (const float*)d_in[13];
  float* out = (float*)d_out;
  float* ws = (float*)d_ws;

  // workspace layout (floats), all f4-aligned
  float* PART_EIF = ws;                       // 1024*768 = 786432
  float* PART_ETF = PART_EIF + 786432;        // 1024*768 = 786432
  float* MSUM_ETF = PART_ETF + 786432;        // 2048
  float* M_MEAN   = MSUM_ETF + 2048;          // 320*768 = 245760
  float* Q        = M_MEAN   + 245760;        // 320
  float* V_MT     = Q        + 320;           // 24576
  float* V_MI     = V_MT     + 24576;         // 24576
  float* MTET     = V_MI     + 24576;         // 512
  float* P_BUF    = MTET     + 512;           // 5120

  // D1: mof -> m_mean/q, mif -> v_mi, mtf -> v_mt, mtet
  d1_k<<<470, 384, 0, stream>>>(mof, mos, mif, mtf, mtm, etf, msp, mep,
                                M_MEAN, Q, V_MI, V_MT, MTET);

  // D2: eof-dot + eif/etf partials (one big streamer)
  d2_k<<<3755, 192, 0, stream>>>(eofp, eif, etf, etm, M_MEAN, Q, eos,
                                 PART_EIF, PART_ETF, MSUM_ETF, P_BUF);

  // D3: combines + miei + GCN + final cosine
  d3_k<<<B_, 384, 0, stream>>>(PART_EIF, PART_ETF, MSUM_ETF, P_BUF, mos, eos,
                               V_MT, V_MI, MTET, mtei, miet, out);
}

// Round 7
// 194.005 us; speedup vs baseline: 1.2542x; 1.0865x over previous
//
#include <hip/hip_runtime.h>

#define EPSF 1e-8f

// Dimensions
#define B_  32
#define C_  16
#define L_  128
#define D_  768
#define D4_ 192   // D/4
#define P_  196
#define OM_ 10
#define OE_ 10
#define R_  36

typedef float f4 __attribute__((ext_vector_type(4)));

__device__ __forceinline__ float f4dot(f4 a, f4 b){ return a.x*b.x + a.y*b.y + a.z*b.z + a.w*b.w; }
__device__ __forceinline__ f4 ldnt(const f4* p){ return __builtin_nontemporal_load(p); }
__device__ __forceinline__ float wave_sum(float v){
  #pragma unroll
  for (int off = 32; off > 0; off >>= 1) v += __shfl_down(v, off);
  return v;  // valid on lane 0
}

// ================= D1: everything except eof (577 MB) =================
// Block table (192 threads = 3 waves):
//   [0,1024)      eif partials: idx=blk, g=idx>>1, ch=idx&1, 98 rows -> part_eif
//   [1024,2048)   etf partials (masked): g=(blk-1024)>>1, ch=&1, 64 rows -> part_etf, msum_etf
//   [2048,2368)   mof: block per (b,i), 36 rows -> m_mean, q
//   [2368,2592)   mif partials: idx=blk-2368, b=idx/7, ch=idx%7, 28 rows -> part_mif
//   [2592,2720)   mtf partials (masked): idx=blk-2592, b=idx>>2, ch=idx&3, 32 rows -> part_mtf, msum_mtf
//   [2720,2891)   mtet: wave per (b,c), w=(blk-2720)*3+wv < 512
__global__ __launch_bounds__(192)
void d1_k(const float* __restrict__ eif, const float* __restrict__ etf,
          const float* __restrict__ etm, const float* __restrict__ mof,
          const float* __restrict__ mos, const float* __restrict__ mif,
          const float* __restrict__ mtf, const float* __restrict__ mtm,
          const int* __restrict__ msp, const int* __restrict__ mep,
          float* __restrict__ part_eif, float* __restrict__ part_etf,
          float* __restrict__ msum_etf,
          float* __restrict__ m_mean, float* __restrict__ q,
          float* __restrict__ part_mif, float* __restrict__ part_mtf,
          float* __restrict__ msum_mtf, float* __restrict__ mtet)
{
  int blk = blockIdx.x, t = threadIdx.x;

  if (blk < 1024) {
    // ---- eif partials (CH=2, 98 rows) ----
    int g = blk >> 1, ch = blk & 1;
    const f4* inp = (const f4*)eif + ((size_t)g * P_ + ch * 98) * D4_;
    f4 acc = {0.f,0.f,0.f,0.f};
    #pragma unroll 4
    for (int r = 0; r < 98; ++r) acc += ldnt(inp + (size_t)r * D4_ + t);
    ((f4*)part_eif)[(size_t)blk * D4_ + t] = acc;
    return;
  }
  if (blk < 2048) {
    // ---- etf partials (CH=2, 64 rows, masked) ----
    int idx = blk - 1024;
    int g = idx >> 1, ch = idx & 1;
    const f4* inp = (const f4*)etf + ((size_t)g * L_ + ch * 64) * D4_;
    const float* mrow = etm + (size_t)g * L_ + ch * 64;
    f4 acc = {0.f,0.f,0.f,0.f};
    float ms = 0.f;
    #pragma unroll 4
    for (int r = 0; r < 64; ++r) {
      float w = mrow[r];
      acc += ldnt(inp + (size_t)r * D4_ + t) * w;
      ms += w;
    }
    ((f4*)part_etf)[(size_t)idx * D4_ + t] = acc;
    if (t == 0) msum_etf[idx] = ms;
    return;
  }
  if (blk < 2368) {
    // ---- mof -> m_mean[g], q[g]; g = b*10+i, 36 rows ----
    __shared__ float shs[3];
    int g = blk - 2048;
    const f4* base = (const f4*)mof + (size_t)g * R_ * D4_;
    f4 acc = {0.f, 0.f, 0.f, 0.f};
    #pragma unroll 6
    for (int r = 0; r < R_; ++r) acc += ldnt(base + (size_t)r * D4_ + t);
    acc *= (1.f / 36.f);
    ((f4*)m_mean)[(size_t)g * D4_ + t] = acc;
    float n = wave_sum(f4dot(acc, acc));
    if ((t & 63) == 0) shs[t >> 6] = n;
    __syncthreads();
    if (t == 0) q[g] = mos[g] / fmaxf(sqrtf(shs[0] + shs[1] + shs[2]), EPSF);
    return;
  }
  if (blk < 2592) {
    // ---- mif partials (CH=7, 28 rows) ----
    int idx = blk - 2368;
    int b = idx / 7, ch = idx - b * 7;
    const f4* inp = (const f4*)mif + ((size_t)b * P_ + ch * 28) * D4_;
    f4 acc = {0.f,0.f,0.f,0.f};
    #pragma unroll 4
    for (int r = 0; r < 28; ++r) acc += ldnt(inp + (size_t)r * D4_ + t);
    ((f4*)part_mif)[(size_t)idx * D4_ + t] = acc;
    return;
  }
  if (blk < 2720) {
    // ---- mtf partials (CH=4, 32 rows, masked) ----
    int idx = blk - 2592;
    int b = idx >> 2, ch = idx & 3;
    const f4* inp = (const f4*)mtf + ((size_t)b * L_ + ch * 32) * D4_;
    const float* mrow = mtm + (size_t)b * L_ + ch * 32;
    f4 acc = {0.f,0.f,0.f,0.f};
    float ms = 0.f;
    #pragma unroll 4
    for (int r = 0; r < 32; ++r) {
      float w = mrow[r];
      acc += ldnt(inp + (size_t)r * D4_ + t) * w;
      ms += w;
    }
    ((f4*)part_mtf)[(size_t)idx * D4_ + t] = acc;
    if (t == 0) msum_mtf[idx] = ms;
    return;
  }
  {
    // ---- mtet: wave per (b,c) ----
    int w = (blk - 2720) * 3 + (t >> 6);
    if (w >= B_ * C_) return;
    int lane = t & 63;
    int b = w >> 4;
    const f4* ecls = (const f4*)etf + (size_t)w * L_ * D4_;  // l = 0
    const f4* mb   = (const f4*)mtf + (size_t)b * L_ * D4_;
    int sp = msp[b], ep = mep[b];
    float dt = 0.f, na = 0.f, nb = 0.f;
    #pragma unroll
    for (int k = 0; k < 3; ++k) {
      f4 a = (mb[(size_t)sp * D4_ + lane + 64*k] + mb[(size_t)ep * D4_ + lane + 64*k]) * 0.5f;
      f4 e = ecls[lane + 64*k];
      dt += f4dot(a, e); na += f4dot(a, a); nb += f4dot(e, e);
    }
    dt = wave_sum(dt); na = wave_sum(na); nb = wave_sum(nb);
    if (lane == 0) mtet[w] = dt / fmaxf(sqrtf(na) * sqrtf(nb), EPSF);
  }
}

// ================= D2: eof-dot only (566 MB) =================
// wave per g = blk*3+wv (g<5120) -> p[g]
__global__ __launch_bounds__(192)
void d2_k(const float* __restrict__ eofp, const float* __restrict__ m_mean,
          const float* __restrict__ q, const float* __restrict__ eos,
          float* __restrict__ p)
{
  int blk = blockIdx.x, t = threadIdx.x;
  int wave = t >> 6, lane = t & 63;
  int g = blk * 3 + wave;              // g = bc*10 + j
  if (g >= B_ * C_ * OE_) return;
  int b = g / (C_ * OE_);
  const f4* ep = (const f4*)eofp + (size_t)g * R_ * D4_;
  f4 a0 = {0.f,0.f,0.f,0.f}, a1 = a0, a2 = a0;
  #pragma unroll 4
  for (int r = 0; r < R_; ++r) {
    const f4* row = ep + (size_t)r * D4_;
    a0 += ldnt(row + lane);
    a1 += ldnt(row + lane + 64);
    a2 += ldnt(row + lane + 128);
  }
  const float inv36 = 1.f / 36.f;
  a0 *= inv36; a1 *= inv36; a2 *= inv36;
  float nrm = f4dot(a0, a0) + f4dot(a1, a1) + f4dot(a2, a2);
  float s = 0.f;
  const f4* mp = (const f4*)m_mean + (size_t)b * OM_ * D4_;
  #pragma unroll
  for (int i = 0; i < OM_; ++i) {
    const f4* mr = mp + (size_t)i * D4_;
    float di = f4dot(a0, mr[lane]) + f4dot(a1, mr[lane + 64]) + f4dot(a2, mr[lane + 128]);
    s += q[b * OM_ + i] * di;
  }
  s = wave_sum(s); nrm = wave_sum(nrm);
  if (lane == 0) p[g] = eos[g] * s / fmaxf(sqrtf(nrm), EPSF);
}

// ================= D3: all combines (LDS) + miei + GCN + final =================
__global__ __launch_bounds__(384)
void d3_k(const float* __restrict__ part_eif, const float* __restrict__ part_etf,
          const float* __restrict__ msum_etf,
          const float* __restrict__ part_mif, const float* __restrict__ part_mtf,
          const float* __restrict__ msum_mtf,
          const float* __restrict__ p, const float* __restrict__ mos,
          const float* __restrict__ eos,
          const float* __restrict__ mtet, const float* __restrict__ mtei,
          const float* __restrict__ miet,
          float* __restrict__ out)
{
  __shared__ float s_vet[C_][D_];                      // 48 KiB
  __shared__ float sh_vmt[D_], sh_vmi[D_];             // 6 KiB
  __shared__ float sh_e0[C_], sh_e1[C_], sh_e2[C_], sh_e3[C_];
  __shared__ float sh_m[D_], sh_s[D_];                 // 6 KiB
  int b = blockIdx.x, t = threadIdx.x;

  // 1) combines into LDS
  // v_et: CH=2 + mask-sum
  for (int it = t; it < C_ * D4_; it += 384) {
    int c = it / D4_, col = it - c * D4_;
    int i2 = (b * C_ + c) * 2;
    f4 a = ((const f4*)part_etf)[(size_t)i2 * D4_ + col]
         + ((const f4*)part_etf)[(size_t)(i2 + 1) * D4_ + col];
    float scale = 1.f / fmaxf(msum_etf[i2] + msum_etf[i2 + 1], 1.f);
    ((f4*)&s_vet[c][0])[col] = a * scale;
  }
  // v_mt (CH=4 masked), v_mi (CH=7)
  if (t < D4_) {
    int col = t;
    f4 a = {0.f,0.f,0.f,0.f};
    #pragma unroll
    for (int ch = 0; ch < 4; ++ch)
      a += ((const f4*)part_mtf)[(size_t)(b * 4 + ch) * D4_ + col];
    float ms = msum_mtf[b*4] + msum_mtf[b*4+1] + msum_mtf[b*4+2] + msum_mtf[b*4+3];
    ((f4*)sh_vmt)[col] = a * (1.f / fmaxf(ms, 1.f));
    f4 v = {0.f,0.f,0.f,0.f};
    #pragma unroll
    for (int ch = 0; ch < 7; ++ch)
      v += ((const f4*)part_mif)[(size_t)(b * 7 + ch) * D4_ + col];
    ((f4*)sh_vmi)[col] = v * (1.f / 196.f);
  }
  // edges
  if (t >= 256 && t < 256 + C_) {
    int c = t - 256;
    int bc = b * C_ + c;
    float num = 0.f, se = 0.f, sm = 0.f;
    #pragma unroll
    for (int j = 0; j < OE_; ++j) { num += p[bc * OE_ + j]; se += eos[bc * OE_ + j]; }
    #pragma unroll
    for (int i = 0; i < OM_; ++i) sm += mos[b * OM_ + i];
    sh_e3[c] = num / (sm * se);      // miei
    sh_e0[c] = mtet[bc];
    sh_e1[c] = mtei[bc];
    sh_e2[c] = miet[bc];
  }
  __syncthreads();

  // 2) collapsed GCN
  const float invC = 1.f / (float)C_, inv196 = 1.f / 196.f;
  for (int d = t; d < D_; d += 384) {
    float vmt = sh_vmt[d], vmi = sh_vmi[d];
    float nv0 = 0.f, nv1 = 0.f, macc = 0.f;
    #pragma unroll
    for (int c = 0; c < C_; ++c) {
      int i2 = (b * C_ + c) * 2;
      float et = s_vet[c][d];
      float ei = (part_eif[(size_t)i2 * D_ + d] + part_eif[(size_t)(i2 + 1) * D_ + d]) * inv196;
      float e0 = sh_e0[c], e1 = sh_e1[c], e2 = sh_e2[c], e3 = sh_e3[c];
      nv0 += e0 * et + e1 * ei;
      nv1 += e2 * et + e3 * ei;
      macc += (vmt * et) * (e0 * vmt + e2 * vmi)
            + (vmt * ei) * (e1 * vmt + e3 * vmi);
    }
    sh_m[d] = macc * invC;
    sh_s[d] = vmt * (nv0 * invC) + vmi * (nv1 * invC);
  }
  __syncthreads();

  // 3) final cosine: wave per c
  int wv = t >> 6, lane = t & 63;
  for (int c = wv; c < C_; c += 6) {
    const f4* ep = (const f4*)&s_vet[c][0];
    const f4* mp = (const f4*)sh_m;
    const f4* sp = (const f4*)sh_s;
    float dt = 0.f, nm = 0.f, ne = 0.f;
    #pragma unroll
    for (int k = 0; k < 3; ++k) {
      f4 m = mp[lane + 64*k];
      f4 sv = sp[lane + 64*k];
      f4 e = ep[lane + 64*k];
      f4 ent = e * sv;
      dt += f4dot(m, ent); nm += f4dot(m, m); ne += f4dot(ent, ent);
    }
    dt = wave_sum(dt); nm = wave_sum(nm); ne = wave_sum(ne);
    if (lane == 0) out[b * C_ + c] = dt / fmaxf(sqrtf(nm) * sqrtf(ne), EPSF);
  }
}

extern "C" void kernel_launch(void* const* d_in, const int* in_sizes, int n_in,
                              void* d_out, int out_size, void* d_ws, size_t ws_size,
                              hipStream_t stream)
{
  const float* mtf  = (const float*)d_in[0];
  const float* mtm  = (const float*)d_in[1];
  const int*   msp  = (const int*)  d_in[2];
  const int*   mep  = (const int*)  d_in[3];
  const float* mif  = (const float*)d_in[4];
  const float* mof  = (const float*)d_in[5];
  const float* mos  = (const float*)d_in[6];
  const float* etf  = (const float*)d_in[7];
  const float* etm  = (const float*)d_in[8];
  const float* eif  = (const float*)d_in[9];
  const float* eofp = (const float*)d_in[10];
  const float* eos  = (const float*)d_in[11];
  const float* miet = (const float*)d_in[12];
  const float* mtei = (const float*)d_in[13];
  float* out = (float*)d_out;
  float* ws = (float*)d_ws;

  // workspace layout (floats), all f4-aligned
  float* PART_EIF = ws;                       // 1024*768 = 786432
  float* PART_ETF = PART_EIF + 786432;        // 1024*768 = 786432
  float* MSUM_ETF = PART_ETF + 786432;        // 1024
  float* PART_MIF = MSUM_ETF + 1024;          // 224*768 = 172032
  float* PART_MTF = PART_MIF + 172032;        // 128*768 = 98304
  float* MSUM_MTF = PART_MTF + 98304;         // 128
  float* M_MEAN   = MSUM_MTF + 128;           // 320*768 = 245760
  float* Q        = M_MEAN   + 245760;        // 320
  float* MTET     = Q        + 320;           // 512
  float* P_BUF    = MTET     + 512;           // 5120

  // D1: everything except eof (577 MB)
  d1_k<<<2891, 192, 0, stream>>>(eif, etf, etm, mof, mos, mif, mtf, mtm,
                                 msp, mep,
                                 PART_EIF, PART_ETF, MSUM_ETF,
                                 M_MEAN, Q, PART_MIF, PART_MTF, MSUM_MTF, MTET);

  // D2: eof-dot (566 MB)
  d2_k<<<1707, 192, 0, stream>>>(eofp, M_MEAN, Q, eos, P_BUF);

  // D3: combines + miei + GCN + final cosine
  d3_k<<<B_, 384, 0, stream>>>(PART_EIF, PART_ETF, MSUM_ETF,
                               PART_MIF, PART_MTF, MSUM_MTF,
                               P_BUF, mos, eos, MTET, mtei, miet, out);
}